// Round 4
// baseline (1829.057 us; speedup 1.0000x reference)
//
#include <hip/hip_runtime.h>
#include <cstdint>
#include <cstddef>

// Problem: B=64, T=512, I=128, H=256, 4H=1024, C=3. All fp32 in/out.
typedef _Float16 half2_t __attribute__((ext_vector_type(2)));
typedef _Float16 half8_t __attribute__((ext_vector_type(8)));
typedef float f32x4 __attribute__((ext_vector_type(4)));

static __device__ __forceinline__ float fdot2(half2_t a, half2_t b, float c) {
    return __builtin_amdgcn_fdot2(a, b, c, false);
}
static __device__ __forceinline__ half2_t h2(unsigned int u) {
    return __builtin_bit_cast(half2_t, u);
}
static __device__ __forceinline__ float sigm(float x) {
    return 1.f / (1.f + __expf(-x));
}
static __device__ __forceinline__ float tanh_fast(float x) {
    float ax = fabsf(x);
    float e = __expf(2.f * ax);
    float r = 1.f - 2.f / (e + 1.f);
    return copysignf(r, x);
}

// ---------------------------------------------------------------------------
// prep: W_hh (1024x256 fp32) -> f16 plane layout for the scan.
// plane p = g*16+u (g=gate 0..3, u=k8-sub 0..15), entry idx = q*256+j:
//   Wp[p*512+idx] = 8 halves of W[g*256+j][q*128 + u*8 ..]
// bias = b_ih + b_hh
// ---------------------------------------------------------------------------
__global__ __launch_bounds__(256) void prep_whh(const float* __restrict__ Whh,
                                                const float* __restrict__ bih,
                                                const float* __restrict__ bhh,
                                                uint4* __restrict__ Wp,
                                                float* __restrict__ bias) {
    int n = blockIdx.x * 256 + threadIdx.x;  // 0..32767
    if (n < 1024) bias[n] = bih[n] + bhh[n];
    int p = n >> 9;         // plane 0..63
    int idx = n & 511;      // q*256 + j
    int qq = idx >> 8, jj = idx & 255;
    int g = p >> 4, u = p & 15;
    int row = g * 256 + jj;
    int kb = qq * 128 + u * 8;
    union { uint4 u4; _Float16 h[8]; } cv;
#pragma unroll
    for (int i = 0; i < 8; ++i) cv.h[i] = (_Float16)Whh[row * 256 + kb + i];
    Wp[p * 512 + idx] = cv.u4;
}

// f32 -> f16, 4 elements/thread
__global__ __launch_bounds__(256) void cvt_f16(const float* __restrict__ in,
                                               _Float16* __restrict__ out, int n4) {
    int i = blockIdx.x * 256 + threadIdx.x;
    if (i < n4) {
        float4 v = ((const float4*)in)[i];
        union { ushort4 u; _Float16 h[4]; } cv;
        cv.h[0] = (_Float16)v.x; cv.h[1] = (_Float16)v.y;
        cv.h[2] = (_Float16)v.z; cv.h[3] = (_Float16)v.w;
        ((ushort4*)out)[i] = cv.u;
    }
}

// ---------------------------------------------------------------------------
// gemm_mfma: C[M][1024] = A[M][K](f16) * W[1024][K](f16)^T + bias, fp32 out.
// ---------------------------------------------------------------------------
__global__ __launch_bounds__(256) void gemm_mfma(const _Float16* __restrict__ A,
                                                 const _Float16* __restrict__ Bw,
                                                 const float* __restrict__ bias,
                                                 float* __restrict__ Cmat, int K) {
    __shared__ _Float16 As[64][72];
    __shared__ _Float16 Bs[64][72];
    const int tid = threadIdx.x;
    const int wave = tid >> 6, lane = tid & 63;
    const int quad = lane >> 4, l16 = lane & 15;
    const int m0 = blockIdx.x * 64, n0 = blockIdx.y * 64;
    const int sr = tid >> 2;
    const int sc = (tid & 3) * 16;

    f32x4 acc[4] = {};

    for (int k0 = 0; k0 < K; k0 += 64) {
        const uint4 a0v = *(const uint4*)(A + (size_t)(m0 + sr) * K + k0 + sc);
        const uint4 a1v = *(const uint4*)(A + (size_t)(m0 + sr) * K + k0 + sc + 8);
        const uint4 b0v = *(const uint4*)(Bw + (size_t)(n0 + sr) * K + k0 + sc);
        const uint4 b1v = *(const uint4*)(Bw + (size_t)(n0 + sr) * K + k0 + sc + 8);
        __syncthreads();
        *(uint4*)&As[sr][sc] = a0v;
        *(uint4*)&As[sr][sc + 8] = a1v;
        *(uint4*)&Bs[sr][sc] = b0v;
        *(uint4*)&Bs[sr][sc + 8] = b1v;
        __syncthreads();
#pragma unroll
        for (int kc = 0; kc < 64; kc += 32) {
            half8_t af = *(const half8_t*)&As[wave * 16 + l16][kc + quad * 8];
#pragma unroll
            for (int nb = 0; nb < 4; ++nb) {
                half8_t bf = *(const half8_t*)&Bs[nb * 16 + l16][kc + quad * 8];
                acc[nb] = __builtin_amdgcn_mfma_f32_16x16x32_f16(af, bf, acc[nb], 0, 0, 0);
            }
        }
    }
#pragma unroll
    for (int nb = 0; nb < 4; ++nb) {
#pragma unroll
        for (int i = 0; i < 4; ++i) {
            int row = m0 + wave * 16 + quad * 4 + i;
            int col = n0 + nb * 16 + l16;
            Cmat[(size_t)row * 1024 + col] = acc[nb][i] + bias[col];
        }
    }
}

// ---------------------------------------------------------------------------
// lstm_scan v9: 64 WGs x 512 thr (8 waves = 2 waves/SIMD, 256-reg budget).
// Same decomposition as v8 (thread tid=q*256+j, 4 gate partials of unit j
// over K-half q), but the h K-half is now broadcast THROUGH THE REGISTER
// FILE instead of 16 uniform LDS reads per thread:
//   - each lane does ONE ds_read_b128 (lane i -> h-chunk i&15, 4-way repl.)
//   - the 16-chunk loop uses v_readlane to pull lane u's 4 dwords to SGPRs;
//     fdot2 consumes the uniform half2 from the scalar bus.
// h LDS traffic: 128 wave-ops/step -> 8. Math is bitwise identical to v8.
// LDS-op budget/step: 128 wlds b128 (~1536cy) + 8 h + ~24 pex/hist ~ 1900cy.
// Weights: 48 uint4 (gates i,f,g) persistent in unified regfile, 16 planes
// (gate o, 128 KB) in LDS. 2 barriers/step.
// ---------------------------------------------------------------------------
__global__ __launch_bounds__(512, 2)
void lstm_scan(const float* __restrict__ gx,
               const uint4* __restrict__ Wp,
               _Float16* __restrict__ h_out,
               int store_all) {
    const int b = blockIdx.x;
    const int tid = threadIdx.x;   // = q*256 + j
    const int q = tid >> 8;        // K-half 0/1 (wave-uniform)
    const int j = tid & 255;       // hidden unit
    const int l = tid & 63;        // lane

    __shared__ uint4 wlds[16 * 512];                                 // 128 KB (gate o)
    __shared__ f32x4 pex[512] __attribute__((aligned(16)));          // 8 KB
    __shared__ _Float16 hbuf[2][256] __attribute__((aligned(16)));   // 1 KB
    __shared__ _Float16 hist[8][256] __attribute__((aligned(16)));   // 4 KB

    // stage gate-o planes into LDS
#pragma unroll
    for (int p = 0; p < 16; ++p) wlds[p * 512 + tid] = Wp[(48 + p) * 512 + tid];
    // persistent register weights: gates i,f,g (planes 0..47, 192 regs)
    uint4 wreg[48];
#pragma unroll
    for (int p = 0; p < 48; ++p) wreg[p] = Wp[p * 512 + tid];

    if (tid < 256) hbuf[0][tid] = (_Float16)0.f;
    float c = 0.f;
    // this thread folds gx rows {2q*256+j, (2q+1)*256+j} into its partials
    const float* gxb = gx + (size_t)b * 512 * 1024 + (size_t)(q * 512 + j);
    float gA = gxb[0], gB = gxb[256];
    __syncthreads();  // wlds + hbuf[0] visible

    for (int t = 0; t < 512; ++t) {
        // prefetch next step's gx
        float gA_n = 0.f, gB_n = 0.f;
        if (t < 511) {
            gA_n = gxb[(size_t)(t + 1) * 1024];
            gB_n = gxb[(size_t)(t + 1) * 1024 + 256];
        }

        // ONE b128 per lane: lane l holds h-chunk (l&15) of this wave's K-half
        const char* hpB = (const char*)&hbuf[t & 1][0] + q * 256;
        const uint4 hv4 = *(const uint4*)(hpB + (l & 15) * 16);

        float a0 = 0.f, a1 = 0.f, a2 = 0.f, a3 = 0.f;
#pragma unroll
        for (int u = 0; u < 16; ++u) {
            // broadcast chunk u (held by lane u) to the scalar bus
            const unsigned hx = (unsigned)__builtin_amdgcn_readlane((int)hv4.x, u);
            const unsigned hy = (unsigned)__builtin_amdgcn_readlane((int)hv4.y, u);
            const unsigned hz = (unsigned)__builtin_amdgcn_readlane((int)hv4.z, u);
            const unsigned hw = (unsigned)__builtin_amdgcn_readlane((int)hv4.w, u);
            const uint4 w0 = wreg[u];
            const uint4 w1 = wreg[16 + u];
            const uint4 w2 = wreg[32 + u];
            const uint4 w3 = wlds[u * 512 + tid];
            a0 = fdot2(h2(w0.x), h2(hx), a0);
            a1 = fdot2(h2(w1.x), h2(hx), a1);
            a2 = fdot2(h2(w2.x), h2(hx), a2);
            a3 = fdot2(h2(w3.x), h2(hx), a3);
            a0 = fdot2(h2(w0.y), h2(hy), a0);
            a1 = fdot2(h2(w1.y), h2(hy), a1);
            a2 = fdot2(h2(w2.y), h2(hy), a2);
            a3 = fdot2(h2(w3.y), h2(hy), a3);
            a0 = fdot2(h2(w0.z), h2(hz), a0);
            a1 = fdot2(h2(w1.z), h2(hz), a1);
            a2 = fdot2(h2(w2.z), h2(hz), a2);
            a3 = fdot2(h2(w3.z), h2(hz), a3);
            a0 = fdot2(h2(w0.w), h2(hw), a0);
            a1 = fdot2(h2(w1.w), h2(hw), a1);
            a2 = fdot2(h2(w2.w), h2(hw), a2);
            a3 = fdot2(h2(w3.w), h2(hw), a3);
        }
        // fold gx once per gate row (q=0 folds gates i,f; q=1 folds g,o)
        if (q == 0) { a0 += gA; a1 += gB; }
        else        { a2 += gA; a3 += gB; }

        f32x4 pv = {a0, a1, a2, a3};
        pex[tid] = pv;
        gA = gA_n; gB = gB_n;
        __syncthreads();  // barrier1: pex visible; all hbuf[t&1] reads done

        if (tid < 256) {
            const f32x4 v0 = pex[tid];        // q=0 partials for unit tid
            const f32x4 v1 = pex[256 + tid];  // q=1 partials
            const float ai = v0[0] + v1[0];
            const float af = v0[1] + v1[1];
            const float ag = v0[2] + v1[2];
            const float ao = v0[3] + v1[3];
            const float iv = sigm(ai);
            const float fv = sigm(af);
            const float gv = tanh_fast(ag);
            const float ov = sigm(ao);
            c = fv * c + iv * gv;
            const _Float16 hh = (_Float16)(ov * tanh_fast(c));
            hbuf[(t + 1) & 1][tid] = hh;
            if (store_all) hist[t & 7][tid] = hh;
        }
        __syncthreads();  // barrier2: new h + hist visible

        if (store_all && (t & 7) == 7) {
            // flush 8 steps (4 KB) with all 512 threads (8 B each)
            const uint2 v = ((const uint2*)hist)[tid];
            *(uint2*)(h_out + (size_t)b * 512 * 256 + (size_t)(t - 7) * 256 + tid * 4) = v;
        }
    }
    if (!store_all && tid < 256) {
        // final h lives in hbuf[0] (512 & 1 == 0)
        h_out[(size_t)b * 256 + tid] = hbuf[0][tid];
    }
}

// ---------------------------------------------------------------------------
// fc_softmax: logits = hlast[b,:](f16) @ fc_w^T + fc_b, softmax over 3
// ---------------------------------------------------------------------------
__global__ __launch_bounds__(64) void fc_softmax(const _Float16* __restrict__ hlast,
                                                 const float* __restrict__ fcw,
                                                 const float* __restrict__ fcb,
                                                 float* __restrict__ out) {
    const int b = blockIdx.x;
    const int lane = threadIdx.x;
    const _Float16* h = hlast + (size_t)b * 256;
    float p0 = 0.f, p1 = 0.f, p2 = 0.f;
    for (int k = lane; k < 256; k += 64) {
        float hv = (float)h[k];
        p0 += hv * fcw[k];
        p1 += hv * fcw[256 + k];
        p2 += hv * fcw[512 + k];
    }
#pragma unroll
    for (int off = 32; off > 0; off >>= 1) {
        p0 += __shfl_down(p0, off);
        p1 += __shfl_down(p1, off);
        p2 += __shfl_down(p2, off);
    }
    if (lane == 0) {
        float l0 = p0 + fcb[0], l1 = p1 + fcb[1], l2 = p2 + fcb[2];
        float m = fmaxf(l0, fmaxf(l1, l2));
        float e0 = __expf(l0 - m), e1 = __expf(l1 - m), e2 = __expf(l2 - m);
        float s = 1.f / (e0 + e1 + e2);
        out[b * 3 + 0] = e0 * s;
        out[b * 3 + 1] = e1 * s;
        out[b * 3 + 2] = e2 * s;
    }
}

extern "C" void kernel_launch(void* const* d_in, const int* in_sizes, int n_in,
                              void* d_out, int out_size, void* d_ws, size_t ws_size,
                              hipStream_t stream) {
    const float* x    = (const float*)d_in[0];
    const float* Wih0 = (const float*)d_in[1];
    const float* Whh0 = (const float*)d_in[2];
    const float* bih0 = (const float*)d_in[3];
    const float* bhh0 = (const float*)d_in[4];
    const float* Wih1 = (const float*)d_in[5];
    const float* Whh1 = (const float*)d_in[6];
    const float* bih1 = (const float*)d_in[7];
    const float* bhh1 = (const float*)d_in[8];
    const float* fcw  = (const float*)d_in[9];
    const float* fcb  = (const float*)d_in[10];
    float* out = (float*)d_out;

    // workspace layout (~161 MB)
    char* ws = (char*)d_ws;
    float* gx        = (float*)ws;     ws += (size_t)32768 * 1024 * 4;  // 134.2 MB
    _Float16* h0f    = (_Float16*)ws;  ws += (size_t)32768 * 256 * 2;   // 16.8 MB
    _Float16* xh     = (_Float16*)ws;  ws += (size_t)32768 * 128 * 2;   // 8.4 MB
    _Float16* hlast  = (_Float16*)ws;  ws += (size_t)64 * 256 * 2;      // 32 KB
    _Float16* Wih0h  = (_Float16*)ws;  ws += (size_t)1024 * 128 * 2;    // 256 KB
    _Float16* Wih1h  = (_Float16*)ws;  ws += (size_t)1024 * 256 * 2;    // 512 KB
    uint4* Wp0       = (uint4*)ws;     ws += (size_t)1024 * 256 * 2;    // 512 KB
    uint4* Wp1       = (uint4*)ws;     ws += (size_t)1024 * 256 * 2;    // 512 KB
    float* bias0     = (float*)ws;     ws += 4096;
    float* bias1     = (float*)ws;     ws += 4096;

    prep_whh<<<128, 256, 0, stream>>>(Whh0, bih0, bhh0, Wp0, bias0);
    prep_whh<<<128, 256, 0, stream>>>(Whh1, bih1, bhh1, Wp1, bias1);
    cvt_f16<<<4096, 256, 0, stream>>>(x, xh, 32768 * 128 / 4);
    cvt_f16<<<128, 256, 0, stream>>>(Wih0, Wih0h, 1024 * 128 / 4);
    cvt_f16<<<256, 256, 0, stream>>>(Wih1, Wih1h, 1024 * 256 / 4);

    // layer 0
    gemm_mfma<<<dim3(512, 16), 256, 0, stream>>>(xh, Wih0h, bias0, gx, 128);
    lstm_scan<<<64, 512, 0, stream>>>(gx, Wp0, h0f, 1);

    // layer 1
    gemm_mfma<<<dim3(512, 16), 256, 0, stream>>>(h0f, Wih1h, bias1, gx, 256);
    lstm_scan<<<64, 512, 0, stream>>>(gx, Wp1, hlast, 0);

    fc_softmax<<<64, 64, 0, stream>>>(hlast, fcw, fcb, out);
}

// Round 5
// 1735.677 us; speedup vs baseline: 1.0538x; 1.0538x over previous
//
#include <hip/hip_runtime.h>
#include <cstdint>
#include <cstddef>

// Problem: B=64, T=512, I=128, H=256, 4H=1024, C=3. All fp32 in/out.
typedef _Float16 half2_t __attribute__((ext_vector_type(2)));
typedef _Float16 half8_t __attribute__((ext_vector_type(8)));
typedef float f32x4 __attribute__((ext_vector_type(4)));

static __device__ __forceinline__ float fdot2(half2_t a, half2_t b, float c) {
    return __builtin_amdgcn_fdot2(a, b, c, false);
}
static __device__ __forceinline__ half2_t h2(unsigned int u) {
    return __builtin_bit_cast(half2_t, u);
}
static __device__ __forceinline__ float sigm(float x) {
    return 1.f / (1.f + __expf(-x));
}
static __device__ __forceinline__ float tanh_fast(float x) {
    float ax = fabsf(x);
    float e = __expf(2.f * ax);
    float r = 1.f - 2.f / (e + 1.f);
    return copysignf(r, x);
}

// ---------------------------------------------------------------------------
// prep: W_hh (1024x256 fp32) -> f16 plane layout for the scan.
// plane p = g*16+u (g=gate 0..3, u=k8-sub 0..15), entry idx = q*256+j:
//   Wp[p*512+idx] = 8 halves of W[g*256+j][q*128 + u*8 ..]
// bias = b_ih + b_hh
// ---------------------------------------------------------------------------
__global__ __launch_bounds__(256) void prep_whh(const float* __restrict__ Whh,
                                                const float* __restrict__ bih,
                                                const float* __restrict__ bhh,
                                                uint4* __restrict__ Wp,
                                                float* __restrict__ bias) {
    int n = blockIdx.x * 256 + threadIdx.x;  // 0..32767
    if (n < 1024) bias[n] = bih[n] + bhh[n];
    int p = n >> 9;         // plane 0..63
    int idx = n & 511;      // q*256 + j
    int qq = idx >> 8, jj = idx & 255;
    int g = p >> 4, u = p & 15;
    int row = g * 256 + jj;
    int kb = qq * 128 + u * 8;
    union { uint4 u4; _Float16 h[8]; } cv;
#pragma unroll
    for (int i = 0; i < 8; ++i) cv.h[i] = (_Float16)Whh[row * 256 + kb + i];
    Wp[p * 512 + idx] = cv.u4;
}

// f32 -> f16, 4 elements/thread
__global__ __launch_bounds__(256) void cvt_f16(const float* __restrict__ in,
                                               _Float16* __restrict__ out, int n4) {
    int i = blockIdx.x * 256 + threadIdx.x;
    if (i < n4) {
        float4 v = ((const float4*)in)[i];
        union { ushort4 u; _Float16 h[4]; } cv;
        cv.h[0] = (_Float16)v.x; cv.h[1] = (_Float16)v.y;
        cv.h[2] = (_Float16)v.z; cv.h[3] = (_Float16)v.w;
        ((ushort4*)out)[i] = cv.u;
    }
}

// ---------------------------------------------------------------------------
// gemm_mfma: C[M][1024] = A[M][K](f16) * W[1024][K](f16)^T + bias, fp32 out.
// ---------------------------------------------------------------------------
__global__ __launch_bounds__(256) void gemm_mfma(const _Float16* __restrict__ A,
                                                 const _Float16* __restrict__ Bw,
                                                 const float* __restrict__ bias,
                                                 float* __restrict__ Cmat, int K) {
    __shared__ _Float16 As[64][72];
    __shared__ _Float16 Bs[64][72];
    const int tid = threadIdx.x;
    const int wave = tid >> 6, lane = tid & 63;
    const int quad = lane >> 4, l16 = lane & 15;
    const int m0 = blockIdx.x * 64, n0 = blockIdx.y * 64;
    const int sr = tid >> 2;
    const int sc = (tid & 3) * 16;

    f32x4 acc[4] = {};

    for (int k0 = 0; k0 < K; k0 += 64) {
        const uint4 a0v = *(const uint4*)(A + (size_t)(m0 + sr) * K + k0 + sc);
        const uint4 a1v = *(const uint4*)(A + (size_t)(m0 + sr) * K + k0 + sc + 8);
        const uint4 b0v = *(const uint4*)(Bw + (size_t)(n0 + sr) * K + k0 + sc);
        const uint4 b1v = *(const uint4*)(Bw + (size_t)(n0 + sr) * K + k0 + sc + 8);
        __syncthreads();
        *(uint4*)&As[sr][sc] = a0v;
        *(uint4*)&As[sr][sc + 8] = a1v;
        *(uint4*)&Bs[sr][sc] = b0v;
        *(uint4*)&Bs[sr][sc + 8] = b1v;
        __syncthreads();
#pragma unroll
        for (int kc = 0; kc < 64; kc += 32) {
            half8_t af = *(const half8_t*)&As[wave * 16 + l16][kc + quad * 8];
#pragma unroll
            for (int nb = 0; nb < 4; ++nb) {
                half8_t bf = *(const half8_t*)&Bs[nb * 16 + l16][kc + quad * 8];
                acc[nb] = __builtin_amdgcn_mfma_f32_16x16x32_f16(af, bf, acc[nb], 0, 0, 0);
            }
        }
    }
#pragma unroll
    for (int nb = 0; nb < 4; ++nb) {
#pragma unroll
        for (int i = 0; i < 4; ++i) {
            int row = m0 + wave * 16 + quad * 4 + i;
            int col = n0 + nb * 16 + l16;
            Cmat[(size_t)row * 1024 + col] = acc[nb][i] + bias[col];
        }
    }
}

// ---------------------------------------------------------------------------
// lstm_scan v10: 64 WGs x 512 thr (8 waves, 2 waves/SIMD, 256-reg budget).
// v8 decomposition (thread tid=q*256+j: 4 gate partials of unit j over
// K-half q; h via 16 uniform LDS b128 reads; pex exchange; 2 barriers).
// NEW: the weight stream is split off the LDS pipe:
//   - 44 planes in registers: i[0..15], f[0..15], g[0..11]     (176 VGPRs)
//   - 8 planes in LDS (64 KB): g[12..15], o[0..3]              (64 wave-ops)
//   - 12 planes STREAMED from global/L2 per step: o[4..15]
//     (step-invariant addresses; all 64 WGs share the 512 KB in XCD L2;
//      2-batch static pipeline: 8 issued at step top, 4 at u=8;
//      peak 32 VGPRs in flight; consume distance >= 4 chunks > L2 latency)
// LDS ops/step: h 128 + wlds 64 + pex ~24  (~2600cy) vs v8's ~3350cy.
// Summation order is bitwise identical to v8.
// ---------------------------------------------------------------------------
__global__ __launch_bounds__(512, 2)
void lstm_scan(const float* __restrict__ gx,
               const uint4* __restrict__ Wp,
               _Float16* __restrict__ h_out,
               int store_all) {
    const int b = blockIdx.x;
    const int tid = threadIdx.x;   // = q*256 + j
    const int q = tid >> 8;        // K-half 0/1 (wave-uniform)
    const int j = tid & 255;       // hidden unit

    __shared__ uint4 wlds[8 * 512];                                  // 64 KB
    __shared__ f32x4 pex[512] __attribute__((aligned(16)));          // 8 KB
    __shared__ _Float16 hbuf[2][256] __attribute__((aligned(16)));   // 1 KB
    __shared__ _Float16 hist[8][256] __attribute__((aligned(16)));   // 4 KB

    // stage LDS planes: p=0..3 -> g[12..15] (planes 44..47),
    //                   p=4..7 -> o[0..3]   (planes 48..51)
#pragma unroll
    for (int p = 0; p < 8; ++p) wlds[p * 512 + tid] = Wp[(44 + p) * 512 + tid];
    // persistent register weights: planes 0..43 (i, f, g[0..11])
    uint4 wreg[44];
#pragma unroll
    for (int p = 0; p < 44; ++p) wreg[p] = Wp[p * 512 + tid];
    // streamed plane base: plane 52 = o[4]
    const uint4* wo_base = Wp + (size_t)52 * 512 + tid;

    if (tid < 256) hbuf[0][tid] = (_Float16)0.f;
    float c = 0.f;
    // this thread folds gx rows {2q*256+j, (2q+1)*256+j} into its partials
    const float* gxb = gx + (size_t)b * 512 * 1024 + (size_t)(q * 512 + j);
    float gA = gxb[0], gB = gxb[256];
    __syncthreads();  // wlds + hbuf[0] visible

    for (int t = 0; t < 512; ++t) {
        // issue streamed batch S1: o[4..11] (planes 52..59)
        uint4 wo[12];
#pragma unroll
        for (int p = 0; p < 8; ++p) wo[p] = wo_base[p * 512];

        // prefetch next step's gx
        float gA_n = 0.f, gB_n = 0.f;
        if (t < 511) {
            gA_n = gxb[(size_t)(t + 1) * 1024];
            gB_n = gxb[(size_t)(t + 1) * 1024 + 256];
        }

        const char* hpB = (const char*)&hbuf[t & 1][0] + q * 256;
        float a0 = 0.f, a1 = 0.f, a2 = 0.f, a3 = 0.f;
#pragma unroll
        for (int u = 0; u < 16; ++u) {
            if (u == 8) {
                // issue streamed batch S2: o[12..15] (planes 60..63)
#pragma unroll
                for (int p = 8; p < 12; ++p) wo[p] = wo_base[p * 512];
            }
            const uint4 hv = *(const uint4*)(hpB + u * 16);      // uniform
            const uint4 w0 = wreg[u];                            // gate i
            const uint4 w1 = wreg[16 + u];                       // gate f
            const uint4 w2 = (u < 12) ? wreg[32 + u]             // gate g
                                      : wlds[(u - 12) * 512 + tid];
            const uint4 w3 = (u < 4) ? wlds[(4 + u) * 512 + tid] // gate o
                                     : wo[u - 4];
            a0 = fdot2(h2(w0.x), h2(hv.x), a0);
            a1 = fdot2(h2(w1.x), h2(hv.x), a1);
            a2 = fdot2(h2(w2.x), h2(hv.x), a2);
            a3 = fdot2(h2(w3.x), h2(hv.x), a3);
            a0 = fdot2(h2(w0.y), h2(hv.y), a0);
            a1 = fdot2(h2(w1.y), h2(hv.y), a1);
            a2 = fdot2(h2(w2.y), h2(hv.y), a2);
            a3 = fdot2(h2(w3.y), h2(hv.y), a3);
            a0 = fdot2(h2(w0.z), h2(hv.z), a0);
            a1 = fdot2(h2(w1.z), h2(hv.z), a1);
            a2 = fdot2(h2(w2.z), h2(hv.z), a2);
            a3 = fdot2(h2(w3.z), h2(hv.z), a3);
            a0 = fdot2(h2(w0.w), h2(hv.w), a0);
            a1 = fdot2(h2(w1.w), h2(hv.w), a1);
            a2 = fdot2(h2(w2.w), h2(hv.w), a2);
            a3 = fdot2(h2(w3.w), h2(hv.w), a3);
        }
        // fold gx once per gate row (q=0 folds gates i,f; q=1 folds g,o)
        if (q == 0) { a0 += gA; a1 += gB; }
        else        { a2 += gA; a3 += gB; }

        f32x4 pv = {a0, a1, a2, a3};
        pex[tid] = pv;
        gA = gA_n; gB = gB_n;
        __syncthreads();  // barrier1: pex visible; all hbuf[t&1] reads done

        if (tid < 256) {
            const f32x4 v0 = pex[tid];        // q=0 partials for unit tid
            const f32x4 v1 = pex[256 + tid];  // q=1 partials
            const float ai = v0[0] + v1[0];
            const float af = v0[1] + v1[1];
            const float ag = v0[2] + v1[2];
            const float ao = v0[3] + v1[3];
            const float iv = sigm(ai);
            const float fv = sigm(af);
            const float gv = tanh_fast(ag);
            const float ov = sigm(ao);
            c = fv * c + iv * gv;
            const _Float16 hh = (_Float16)(ov * tanh_fast(c));
            hbuf[(t + 1) & 1][tid] = hh;
            if (store_all) hist[t & 7][tid] = hh;
        }
        __syncthreads();  // barrier2: new h + hist visible

        if (store_all && (t & 7) == 7) {
            // flush 8 steps (4 KB) with all 512 threads (8 B each)
            const uint2 v = ((const uint2*)hist)[tid];
            *(uint2*)(h_out + (size_t)b * 512 * 256 + (size_t)(t - 7) * 256 + tid * 4) = v;
        }
    }
    if (!store_all && tid < 256) {
        // final h lives in hbuf[0] (512 & 1 == 0)
        h_out[(size_t)b * 256 + tid] = hbuf[0][tid];
    }
}

// ---------------------------------------------------------------------------
// fc_softmax: logits = hlast[b,:](f16) @ fc_w^T + fc_b, softmax over 3
// ---------------------------------------------------------------------------
__global__ __launch_bounds__(64) void fc_softmax(const _Float16* __restrict__ hlast,
                                                 const float* __restrict__ fcw,
                                                 const float* __restrict__ fcb,
                                                 float* __restrict__ out) {
    const int b = blockIdx.x;
    const int lane = threadIdx.x;
    const _Float16* h = hlast + (size_t)b * 256;
    float p0 = 0.f, p1 = 0.f, p2 = 0.f;
    for (int k = lane; k < 256; k += 64) {
        float hv = (float)h[k];
        p0 += hv * fcw[k];
        p1 += hv * fcw[256 + k];
        p2 += hv * fcw[512 + k];
    }
#pragma unroll
    for (int off = 32; off > 0; off >>= 1) {
        p0 += __shfl_down(p0, off);
        p1 += __shfl_down(p1, off);
        p2 += __shfl_down(p2, off);
    }
    if (lane == 0) {
        float l0 = p0 + fcb[0], l1 = p1 + fcb[1], l2 = p2 + fcb[2];
        float m = fmaxf(l0, fmaxf(l1, l2));
        float e0 = __expf(l0 - m), e1 = __expf(l1 - m), e2 = __expf(l2 - m);
        float s = 1.f / (e0 + e1 + e2);
        out[b * 3 + 0] = e0 * s;
        out[b * 3 + 1] = e1 * s;
        out[b * 3 + 2] = e2 * s;
    }
}

extern "C" void kernel_launch(void* const* d_in, const int* in_sizes, int n_in,
                              void* d_out, int out_size, void* d_ws, size_t ws_size,
                              hipStream_t stream) {
    const float* x    = (const float*)d_in[0];
    const float* Wih0 = (const float*)d_in[1];
    const float* Whh0 = (const float*)d_in[2];
    const float* bih0 = (const float*)d_in[3];
    const float* bhh0 = (const float*)d_in[4];
    const float* Wih1 = (const float*)d_in[5];
    const float* Whh1 = (const float*)d_in[6];
    const float* bih1 = (const float*)d_in[7];
    const float* bhh1 = (const float*)d_in[8];
    const float* fcw  = (const float*)d_in[9];
    const float* fcb  = (const float*)d_in[10];
    float* out = (float*)d_out;

    // workspace layout (~161 MB)
    char* ws = (char*)d_ws;
    float* gx        = (float*)ws;     ws += (size_t)32768 * 1024 * 4;  // 134.2 MB
    _Float16* h0f    = (_Float16*)ws;  ws += (size_t)32768 * 256 * 2;   // 16.8 MB
    _Float16* xh     = (_Float16*)ws;  ws += (size_t)32768 * 128 * 2;   // 8.4 MB
    _Float16* hlast  = (_Float16*)ws;  ws += (size_t)64 * 256 * 2;      // 32 KB
    _Float16* Wih0h  = (_Float16*)ws;  ws += (size_t)1024 * 128 * 2;    // 256 KB
    _Float16* Wih1h  = (_Float16*)ws;  ws += (size_t)1024 * 256 * 2;    // 512 KB
    uint4* Wp0       = (uint4*)ws;     ws += (size_t)1024 * 256 * 2;    // 512 KB
    uint4* Wp1       = (uint4*)ws;     ws += (size_t)1024 * 256 * 2;    // 512 KB
    float* bias0     = (float*)ws;     ws += 4096;
    float* bias1     = (float*)ws;     ws += 4096;

    prep_whh<<<128, 256, 0, stream>>>(Whh0, bih0, bhh0, Wp0, bias0);
    prep_whh<<<128, 256, 0, stream>>>(Whh1, bih1, bhh1, Wp1, bias1);
    cvt_f16<<<4096, 256, 0, stream>>>(x, xh, 32768 * 128 / 4);
    cvt_f16<<<128, 256, 0, stream>>>(Wih0, Wih0h, 1024 * 128 / 4);
    cvt_f16<<<256, 256, 0, stream>>>(Wih1, Wih1h, 1024 * 256 / 4);

    // layer 0
    gemm_mfma<<<dim3(512, 16), 256, 0, stream>>>(xh, Wih0h, bias0, gx, 128);
    lstm_scan<<<64, 512, 0, stream>>>(gx, Wp0, h0f, 1);

    // layer 1
    gemm_mfma<<<dim3(512, 16), 256, 0, stream>>>(h0f, Wih1h, bias1, gx, 256);
    lstm_scan<<<64, 512, 0, stream>>>(gx, Wp1, hlast, 0);

    fc_softmax<<<64, 64, 0, stream>>>(hlast, fcw, fcb, out);
}

// Round 6
// 1634.859 us; speedup vs baseline: 1.1188x; 1.0617x over previous
//
#include <hip/hip_runtime.h>
#include <cstdint>
#include <cstddef>

// Problem: B=64, T=512, I=128, H=256, 4H=1024, C=3. All fp32 in/out.
typedef _Float16 half2_t __attribute__((ext_vector_type(2)));
typedef _Float16 half8_t __attribute__((ext_vector_type(8)));
typedef float f32x4 __attribute__((ext_vector_type(4)));

static __device__ __forceinline__ float fdot2(half2_t a, half2_t b, float c) {
    return __builtin_amdgcn_fdot2(a, b, c, false);
}
static __device__ __forceinline__ half2_t h2(unsigned int u) {
    return __builtin_bit_cast(half2_t, u);
}
static __device__ __forceinline__ float sigm(float x) {
    return 1.f / (1.f + __expf(-x));
}
static __device__ __forceinline__ float tanh_fast(float x) {
    float ax = fabsf(x);
    float e = __expf(2.f * ax);
    float r = 1.f - 2.f / (e + 1.f);
    return copysignf(r, x);
}

// ---------------------------------------------------------------------------
// prep: W_hh (1024x256 fp32) -> f16 plane layout for the scan.
// plane p = g*16+u (g=gate 0..3, u=k8-sub 0..15), entry idx = q*256+j:
//   Wp[p*512+idx] = 8 halves of W[g*256+j][q*128 + u*8 ..]
// bias = b_ih + b_hh
// ---------------------------------------------------------------------------
__global__ __launch_bounds__(256) void prep_whh(const float* __restrict__ Whh,
                                                const float* __restrict__ bih,
                                                const float* __restrict__ bhh,
                                                uint4* __restrict__ Wp,
                                                float* __restrict__ bias) {
    int n = blockIdx.x * 256 + threadIdx.x;  // 0..32767
    if (n < 1024) bias[n] = bih[n] + bhh[n];
    int p = n >> 9;         // plane 0..63
    int idx = n & 511;      // q*256 + j
    int qq = idx >> 8, jj = idx & 255;
    int g = p >> 4, u = p & 15;
    int row = g * 256 + jj;
    int kb = qq * 128 + u * 8;
    union { uint4 u4; _Float16 h[8]; } cv;
#pragma unroll
    for (int i = 0; i < 8; ++i) cv.h[i] = (_Float16)Whh[row * 256 + kb + i];
    Wp[p * 512 + idx] = cv.u4;
}

// f32 -> f16, 4 elements/thread
__global__ __launch_bounds__(256) void cvt_f16(const float* __restrict__ in,
                                               _Float16* __restrict__ out, int n4) {
    int i = blockIdx.x * 256 + threadIdx.x;
    if (i < n4) {
        float4 v = ((const float4*)in)[i];
        union { ushort4 u; _Float16 h[4]; } cv;
        cv.h[0] = (_Float16)v.x; cv.h[1] = (_Float16)v.y;
        cv.h[2] = (_Float16)v.z; cv.h[3] = (_Float16)v.w;
        ((ushort4*)out)[i] = cv.u;
    }
}

// ---------------------------------------------------------------------------
// gemm_mfma: C[M][1024] = A[M][K](f16) * W[1024][K](f16)^T + bias, fp32 out.
// ---------------------------------------------------------------------------
__global__ __launch_bounds__(256) void gemm_mfma(const _Float16* __restrict__ A,
                                                 const _Float16* __restrict__ Bw,
                                                 const float* __restrict__ bias,
                                                 float* __restrict__ Cmat, int K) {
    __shared__ _Float16 As[64][72];
    __shared__ _Float16 Bs[64][72];
    const int tid = threadIdx.x;
    const int wave = tid >> 6, lane = tid & 63;
    const int quad = lane >> 4, l16 = lane & 15;
    const int m0 = blockIdx.x * 64, n0 = blockIdx.y * 64;
    const int sr = tid >> 2;
    const int sc = (tid & 3) * 16;

    f32x4 acc[4] = {};

    for (int k0 = 0; k0 < K; k0 += 64) {
        const uint4 a0v = *(const uint4*)(A + (size_t)(m0 + sr) * K + k0 + sc);
        const uint4 a1v = *(const uint4*)(A + (size_t)(m0 + sr) * K + k0 + sc + 8);
        const uint4 b0v = *(const uint4*)(Bw + (size_t)(n0 + sr) * K + k0 + sc);
        const uint4 b1v = *(const uint4*)(Bw + (size_t)(n0 + sr) * K + k0 + sc + 8);
        __syncthreads();
        *(uint4*)&As[sr][sc] = a0v;
        *(uint4*)&As[sr][sc + 8] = a1v;
        *(uint4*)&Bs[sr][sc] = b0v;
        *(uint4*)&Bs[sr][sc + 8] = b1v;
        __syncthreads();
#pragma unroll
        for (int kc = 0; kc < 64; kc += 32) {
            half8_t af = *(const half8_t*)&As[wave * 16 + l16][kc + quad * 8];
#pragma unroll
            for (int nb = 0; nb < 4; ++nb) {
                half8_t bf = *(const half8_t*)&Bs[nb * 16 + l16][kc + quad * 8];
                acc[nb] = __builtin_amdgcn_mfma_f32_16x16x32_f16(af, bf, acc[nb], 0, 0, 0);
            }
        }
    }
#pragma unroll
    for (int nb = 0; nb < 4; ++nb) {
#pragma unroll
        for (int i = 0; i < 4; ++i) {
            int row = m0 + wave * 16 + quad * 4 + i;
            int col = n0 + nb * 16 + l16;
            Cmat[(size_t)row * 1024 + col] = acc[nb][i] + bias[col];
        }
    }
}

// ---------------------------------------------------------------------------
// lstm_scan v11: 64 WGs x 512 thr (8 waves, 2 waves/SIMD, 256-reg budget).
// v8 decomposition + two latency fixes:
//  (1) COUNTED-WAIT BARRIERS: __syncthreads() would drain vmcnt(0) every
//      step, exposing the HBM latency of the gx prefetch at both barriers.
//      Replaced with {s_waitcnt lgkmcnt(0); s_barrier} (8-phase-template
//      pattern): LDS visibility is guaranteed, global loads STAY IN FLIGHT
//      across barriers. gx consume slack = one full compute phase.
//  (2) 2-deep software pipeline on the per-chunk LDS reads (hv, w3):
//      chunk u+2's loads issue before chunk u's fdot2 block (~100+ cyc
//      load->use distance guaranteed at source level).
// Weights: 48 planes (i,f,g) in 192 regs, 16 planes (o) in 128 KB LDS.
// Math bitwise identical to v8.
// ---------------------------------------------------------------------------
__global__ __launch_bounds__(512, 2)
void lstm_scan(const float* __restrict__ gx,
               const uint4* __restrict__ Wp,
               _Float16* __restrict__ h_out,
               int store_all) {
    const int b = blockIdx.x;
    const int tid = threadIdx.x;   // = q*256 + j
    const int q = tid >> 8;        // K-half 0/1 (wave-uniform)
    const int j = tid & 255;       // hidden unit

    __shared__ uint4 wlds[16 * 512];                                 // 128 KB (gate o)
    __shared__ f32x4 pex[512] __attribute__((aligned(16)));          // 8 KB
    __shared__ _Float16 hbuf[2][256] __attribute__((aligned(16)));   // 1 KB
    __shared__ _Float16 hist[8][256] __attribute__((aligned(16)));   // 4 KB

    // stage gate-o planes into LDS
#pragma unroll
    for (int p = 0; p < 16; ++p) wlds[p * 512 + tid] = Wp[(48 + p) * 512 + tid];
    // persistent register weights: gates i,f,g (planes 0..47, 192 regs)
    uint4 wreg[48];
#pragma unroll
    for (int p = 0; p < 48; ++p) wreg[p] = Wp[p * 512 + tid];

    if (tid < 256) hbuf[0][tid] = (_Float16)0.f;
    float c = 0.f;
    // this thread folds gx rows {2q*256+j, (2q+1)*256+j} into its partials
    const float* gxb = gx + (size_t)b * 512 * 1024 + (size_t)(q * 512 + j);
    float gA = gxb[0], gB = gxb[256];
    __syncthreads();  // one-time full sync: wlds + hbuf[0] visible

    for (int t = 0; t < 512; ++t) {
        // prefetch next step's gx (global; stays in flight across barriers)
        float gA_n = 0.f, gB_n = 0.f;
        if (t < 511) {
            gA_n = gxb[(size_t)(t + 1) * 1024];
            gB_n = gxb[(size_t)(t + 1) * 1024 + 256];
        }

        const char* hpB = (const char*)&hbuf[t & 1][0] + q * 256;

        // 2-deep LDS software pipeline on hv (h chunk) and w3 (gate-o weights)
        uint4 hv_p[2], w3_p[2];
        hv_p[0] = *(const uint4*)(hpB + 0 * 16);
        w3_p[0] = wlds[0 * 512 + tid];
        hv_p[1] = *(const uint4*)(hpB + 1 * 16);
        w3_p[1] = wlds[1 * 512 + tid];

        float a0 = 0.f, a1 = 0.f, a2 = 0.f, a3 = 0.f;
#pragma unroll
        for (int u = 0; u < 16; ++u) {
            const uint4 hv = hv_p[u & 1];
            const uint4 w3 = w3_p[u & 1];
            if (u < 14) {
                hv_p[u & 1] = *(const uint4*)(hpB + (u + 2) * 16);
                w3_p[u & 1] = wlds[(u + 2) * 512 + tid];
            }
            const uint4 w0 = wreg[u];
            const uint4 w1 = wreg[16 + u];
            const uint4 w2 = wreg[32 + u];
            a0 = fdot2(h2(w0.x), h2(hv.x), a0);
            a1 = fdot2(h2(w1.x), h2(hv.x), a1);
            a2 = fdot2(h2(w2.x), h2(hv.x), a2);
            a3 = fdot2(h2(w3.x), h2(hv.x), a3);
            a0 = fdot2(h2(w0.y), h2(hv.y), a0);
            a1 = fdot2(h2(w1.y), h2(hv.y), a1);
            a2 = fdot2(h2(w2.y), h2(hv.y), a2);
            a3 = fdot2(h2(w3.y), h2(hv.y), a3);
            a0 = fdot2(h2(w0.z), h2(hv.z), a0);
            a1 = fdot2(h2(w1.z), h2(hv.z), a1);
            a2 = fdot2(h2(w2.z), h2(hv.z), a2);
            a3 = fdot2(h2(w3.z), h2(hv.z), a3);
            a0 = fdot2(h2(w0.w), h2(hv.w), a0);
            a1 = fdot2(h2(w1.w), h2(hv.w), a1);
            a2 = fdot2(h2(w2.w), h2(hv.w), a2);
            a3 = fdot2(h2(w3.w), h2(hv.w), a3);
        }
        // fold gx once per gate row (q=0 folds gates i,f; q=1 folds g,o)
        if (q == 0) { a0 += gA; a1 += gB; }
        else        { a2 += gA; a3 += gB; }

        f32x4 pv = {a0, a1, a2, a3};
        pex[tid] = pv;
        gA = gA_n; gB = gB_n;   // compiler waits on THIS step's gx loads here
        // barrier1: pex visible; all hbuf[t&1] reads done. NO vmcnt drain.
        asm volatile("s_waitcnt lgkmcnt(0)" ::: "memory");
        __builtin_amdgcn_s_barrier();
        asm volatile("" ::: "memory");

        if (tid < 256) {
            const f32x4 v0 = pex[tid];        // q=0 partials for unit tid
            const f32x4 v1 = pex[256 + tid];  // q=1 partials
            const float ai = v0[0] + v1[0];
            const float af = v0[1] + v1[1];
            const float ag = v0[2] + v1[2];
            const float ao = v0[3] + v1[3];
            const float iv = sigm(ai);
            const float fv = sigm(af);
            const float gv = tanh_fast(ag);
            const float ov = sigm(ao);
            c = fv * c + iv * gv;
            const _Float16 hh = (_Float16)(ov * tanh_fast(c));
            hbuf[(t + 1) & 1][tid] = hh;
            if (store_all) hist[t & 7][tid] = hh;
        }
        // barrier2: new h + hist visible. NO vmcnt drain.
        asm volatile("s_waitcnt lgkmcnt(0)" ::: "memory");
        __builtin_amdgcn_s_barrier();
        asm volatile("" ::: "memory");

        if (store_all && (t & 7) == 7) {
            // flush 8 steps (4 KB) with all 512 threads (8 B each);
            // the global store stays in flight past the next barriers
            const uint2 v = ((const uint2*)hist)[tid];
            *(uint2*)(h_out + (size_t)b * 512 * 256 + (size_t)(t - 7) * 256 + tid * 4) = v;
        }
    }
    if (!store_all && tid < 256) {
        // final h lives in hbuf[0] (512 & 1 == 0)
        h_out[(size_t)b * 256 + tid] = hbuf[0][tid];
    }
}

// ---------------------------------------------------------------------------
// fc_softmax: logits = hlast[b,:](f16) @ fc_w^T + fc_b, softmax over 3
// ---------------------------------------------------------------------------
__global__ __launch_bounds__(64) void fc_softmax(const _Float16* __restrict__ hlast,
                                                 const float* __restrict__ fcw,
                                                 const float* __restrict__ fcb,
                                                 float* __restrict__ out) {
    const int b = blockIdx.x;
    const int lane = threadIdx.x;
    const _Float16* h = hlast + (size_t)b * 256;
    float p0 = 0.f, p1 = 0.f, p2 = 0.f;
    for (int k = lane; k < 256; k += 64) {
        float hv = (float)h[k];
        p0 += hv * fcw[k];
        p1 += hv * fcw[256 + k];
        p2 += hv * fcw[512 + k];
    }
#pragma unroll
    for (int off = 32; off > 0; off >>= 1) {
        p0 += __shfl_down(p0, off);
        p1 += __shfl_down(p1, off);
        p2 += __shfl_down(p2, off);
    }
    if (lane == 0) {
        float l0 = p0 + fcb[0], l1 = p1 + fcb[1], l2 = p2 + fcb[2];
        float m = fmaxf(l0, fmaxf(l1, l2));
        float e0 = __expf(l0 - m), e1 = __expf(l1 - m), e2 = __expf(l2 - m);
        float s = 1.f / (e0 + e1 + e2);
        out[b * 3 + 0] = e0 * s;
        out[b * 3 + 1] = e1 * s;
        out[b * 3 + 2] = e2 * s;
    }
}

extern "C" void kernel_launch(void* const* d_in, const int* in_sizes, int n_in,
                              void* d_out, int out_size, void* d_ws, size_t ws_size,
                              hipStream_t stream) {
    const float* x    = (const float*)d_in[0];
    const float* Wih0 = (const float*)d_in[1];
    const float* Whh0 = (const float*)d_in[2];
    const float* bih0 = (const float*)d_in[3];
    const float* bhh0 = (const float*)d_in[4];
    const float* Wih1 = (const float*)d_in[5];
    const float* Whh1 = (const float*)d_in[6];
    const float* bih1 = (const float*)d_in[7];
    const float* bhh1 = (const float*)d_in[8];
    const float* fcw  = (const float*)d_in[9];
    const float* fcb  = (const float*)d_in[10];
    float* out = (float*)d_out;

    // workspace layout (~161 MB)
    char* ws = (char*)d_ws;
    float* gx        = (float*)ws;     ws += (size_t)32768 * 1024 * 4;  // 134.2 MB
    _Float16* h0f    = (_Float16*)ws;  ws += (size_t)32768 * 256 * 2;   // 16.8 MB
    _Float16* xh     = (_Float16*)ws;  ws += (size_t)32768 * 128 * 2;   // 8.4 MB
    _Float16* hlast  = (_Float16*)ws;  ws += (size_t)64 * 256 * 2;      // 32 KB
    _Float16* Wih0h  = (_Float16*)ws;  ws += (size_t)1024 * 128 * 2;    // 256 KB
    _Float16* Wih1h  = (_Float16*)ws;  ws += (size_t)1024 * 256 * 2;    // 512 KB
    uint4* Wp0       = (uint4*)ws;     ws += (size_t)1024 * 256 * 2;    // 512 KB
    uint4* Wp1       = (uint4*)ws;     ws += (size_t)1024 * 256 * 2;    // 512 KB
    float* bias0     = (float*)ws;     ws += 4096;
    float* bias1     = (float*)ws;     ws += 4096;

    prep_whh<<<128, 256, 0, stream>>>(Whh0, bih0, bhh0, Wp0, bias0);
    prep_whh<<<128, 256, 0, stream>>>(Whh1, bih1, bhh1, Wp1, bias1);
    cvt_f16<<<4096, 256, 0, stream>>>(x, xh, 32768 * 128 / 4);
    cvt_f16<<<128, 256, 0, stream>>>(Wih0, Wih0h, 1024 * 128 / 4);
    cvt_f16<<<256, 256, 0, stream>>>(Wih1, Wih1h, 1024 * 256 / 4);

    // layer 0
    gemm_mfma<<<dim3(512, 16), 256, 0, stream>>>(xh, Wih0h, bias0, gx, 128);
    lstm_scan<<<64, 512, 0, stream>>>(gx, Wp0, h0f, 1);

    // layer 1
    gemm_mfma<<<dim3(512, 16), 256, 0, stream>>>(h0f, Wih1h, bias1, gx, 256);
    lstm_scan<<<64, 512, 0, stream>>>(gx, Wp1, hlast, 0);

    fc_softmax<<<64, 64, 0, stream>>>(hlast, fcw, fcb, out);
}